// Round 23
// baseline (264.991 us; speedup 1.0000x reference)
//
#include <hip/hip_runtime.h>
#include <hip/hip_bf16.h>
#include <math.h>

#define B_ 4
#define Q_ 512
#define M_ 512
#define P_ 128
#define HID_ 1024
#define H_ 16
#define S_ 64
#define R_ 1024
#define POSLEN_ 1536

typedef short bf16x8 __attribute__((ext_vector_type(8)));
typedef float f32x4 __attribute__((ext_vector_type(4)));
typedef unsigned int u32;
typedef unsigned long long u64;

__device__ __forceinline__ ushort f2bf(float f) {
    u32 u = __float_as_uint(f);
    u32 r = (u + 0x7fffu + ((u >> 16) & 1u)) >> 16;
    return (ushort)r;
}
__device__ __forceinline__ float bf2f(ushort s) {
    return __uint_as_float(((u32)s) << 16);
}
__device__ __forceinline__ void gload16(void* l, const void* g) {
    __builtin_amdgcn_global_load_lds(
        (const __attribute__((address_space(1))) u32*)g,
        (__attribute__((address_space(3))) u32*)l, 16, 0, 0);
}

// ---------------- merged prep kernel: cvt + transpose5 + pack_seg + seg_prep + find_tpos ----------------
// Block ranges: [0,5376) cvt (ctx|posenc|query; content read from ctx_bf rows 512..)
// | [5376,10496) transpose | [10496,18688) pack_seg | 18688 seg_prep | [18689,18691) find_tpos.
__global__ __launch_bounds__(256) void prep_all(
    const float* __restrict__ content, const float* __restrict__ mems,
    const float* __restrict__ posenc,  const float* __restrict__ query,
    ushort* __restrict__ ctx, ushort* __restrict__ pos,
    ushort* __restrict__ qry,
    const float* W0, const float* W1, const float* W2, const float* W3, const float* W4,
    ushort* T0, ushort* T1, ushort* T2, ushort* T3, ushort* T4,
    const int* __restrict__ seg, u64* __restrict__ psego,
    const float* __restrict__ segenc, const float* __restrict__ cb,
    const float* __restrict__ sb, ushort* __restrict__ seg_bf,
    float* __restrict__ segc,
    const float* __restrict__ tm, int* __restrict__ tpos)
{
    __shared__ float t[32][33];
    const int bid = blockIdx.x;
    const int tid = threadIdx.x;

    if (bid < 5376) {
        int v = bid * 256 + tid;
        const float* src;
        ushort* dst;
        if (v < 524288) {
            int row = v >> 7, c8 = v & 127;
            int n = row >> 10, l = row & 1023;
            src = (l < M_) ? mems + ((size_t)(n * M_ + l)) * 1024 + c8 * 8
                           : content + ((size_t)(n * Q_ + (l - M_))) * 1024 + c8 * 8;
            dst = ctx + (size_t)v * 8;
        } else if (v < 1310720) {
            int u = v - 524288;
            src = posenc + (size_t)u * 8; dst = pos + (size_t)u * 8;
        } else {
            int u = v - 1310720;
            src = query + (size_t)u * 8; dst = qry + (size_t)u * 8;
        }
        float4 a = *(const float4*)src;
        float4 b = *(const float4*)(src + 4);
        ushort4 o0 = {f2bf(a.x), f2bf(a.y), f2bf(a.z), f2bf(a.w)};
        ushort4 o1 = {f2bf(b.x), f2bf(b.y), f2bf(b.z), f2bf(b.w)};
        *(ushort4*)dst = o0;
        *(ushort4*)(dst + 4) = o1;
    } else if (bid < 10496) {
        int b2 = bid - 5376;
        int bxw = (b2 & 31) * 32;
        int byw = ((b2 >> 5) & 31) * 32;
        int z = b2 >> 10;
        const float* W; ushort* T;
        switch (z) {
            case 0: W = W0; T = T0; break;
            case 1: W = W1; T = T1; break;
            case 2: W = W2; T = T2; break;
            case 3: W = W3; T = T3; break;
            default: W = W4; T = T4; break;
        }
        int tx = tid & 31, ty = tid >> 5;
        #pragma unroll
        for (int i = 0; i < 32; i += 8)
            t[ty + i][tx] = W[(size_t)(byw + ty + i) * 1024 + bxw + tx];
        __syncthreads();
        #pragma unroll
        for (int i = 0; i < 32; i += 8)
            T[(size_t)(bxw + ty + i) * 1024 + byw + tx] = f2bf(t[tx][ty + i]);
    } else if (bid < 18688) {
        int idx = (bid - 10496) * 256 + tid;
        u64 m = __ballot(seg[idx] > 0);
        if ((tid & 63) == 0) psego[idx >> 6] = m;
    } else if (bid == 18688) {
        for (int tt = tid; tt < 16 * 16 * 64; tt += 256) {
            int h = tt >> 10, g = (tt >> 6) & 15, s = tt & 63;
            float v = (g < 2) ? segenc[(size_t)(g * 16 + h) * 64 + s] : 0.f;
            seg_bf[tt] = f2bf(v);
        }
        if (tid < 32) {
            int h = tid >> 1, g = tid & 1;
            float acc = 0.f;
            for (int s = 0; s < 64; ++s)
                acc += (sb[h * 64 + s] - cb[h * 64 + s]) * segenc[(size_t)(g * 16 + h) * 64 + s];
            segc[h * 2 + g] = acc;
        }
    } else {
        int i = (bid - 18689) * 256 + tid;
        if (i < B_ * P_) {
            const float* row = tm + (size_t)i * Q_;
            int q = 0;
            for (int j = 0; j < Q_; ++j) q = (row[j] > 0.5f) ? j : q;
            tpos[i] = q;
        }
    }
}

// ---------------- merged projection GEMM, tile 128m x 64n (R6 config) + XCD swizzle ----------------
// Bijective XCD swizzle (nwg=2112=8*264), y-major logical order: each XCD's contiguous
// 264-block chunk covers ALL 16 x-blocks of a contiguous y-range, so the shared A
// row-panels (256 KB each) stay in ONE per-XCD L2 instead of being fetched by all 8.
// Qc jobs (y in [112,128)) read A from ctx_bf rows 512.. of each batch (content region).
__global__ __launch_bounds__(256) void proj_all(
    const ushort* __restrict__ ctx, const ushort* __restrict__ pos,
    const ushort* __restrict__ qry,
    const ushort* __restrict__ Wkc_t, const ushort* __restrict__ Wv_t,
    const ushort* __restrict__ Wkp_t, const ushort* __restrict__ Wq_t,
    ushort* __restrict__ KC, ushort* __restrict__ Vt, ushort* __restrict__ KP,
    ushort* __restrict__ Qccb, ushort* __restrict__ Qcpb,
    ushort* __restrict__ Qqcb, ushort* __restrict__ Qqpb,
    const float* __restrict__ cbias, const float* __restrict__ pbias)
{
    __shared__ ushort As[128 * 64];
    __shared__ ushort Bs[64 * 64];

    // XCD swizzle: logical l = y*16 + x (y-major); XCD k owns l in [k*264,(k+1)*264)
    int wg = blockIdx.x + 16 * blockIdx.y;
    int swz = (wg & 7) * 264 + (wg >> 3);
    const int y = swz >> 4;           // swz / 16
    const int xx = swz & 15;          // swz % 16

    const ushort *A, *Bt;
    ushort *O1, *O2 = nullptr;
    const float *b1 = nullptr, *b2 = nullptr;
    int LROWS, MODE, m0;
    if (y < 32)       { A = ctx;  Bt = Wkc_t; O1 = KC;   LROWS = 1024; MODE = 1; m0 = y * 128; }
    else if (y < 64)  { A = ctx;  Bt = Wv_t;  O1 = Vt;   LROWS = 1024; MODE = 2; m0 = (y - 32) * 128; }
    else if (y < 112) { A = pos;  Bt = Wkp_t; O1 = KP;   LROWS = 1536; MODE = 1; m0 = (y - 64) * 128; }
    else if (y < 128) {
        // content Q projection: A rows live inside ctx at n*1024 + 512 + l
        A = ctx + ((size_t)((((y - 112) >> 2) * 512) + 512) * 1024);
        Bt = Wq_t;  O1 = Qccb; O2 = Qcpb; b1 = cbias; b2 = pbias; LROWS = 512; MODE = 1; m0 = (y - 112) * 128;
    }
    else              { A = qry;  Bt = Wq_t;  O1 = Qqcb; O2 = Qqpb; b1 = cbias; b2 = pbias; LROWS = 128; MODE = 1; m0 = (y - 128) * 128; }
    const int nn_blk = m0 / LROWS;
    const int lrbase = m0 - nn_blk * LROWS;

    const int tid = threadIdx.x;
    const int lane = tid & 63, wave = tid >> 6;
    const int l15 = lane & 15, hi = lane >> 4;
    const int wm = wave >> 1, wn = wave & 1;
    const int n0 = xx * 64;

    f32x4 acc[4][2];
    #pragma unroll
    for (int i = 0; i < 4; ++i)
        #pragma unroll
        for (int j = 0; j < 2; ++j) acc[i][j] = f32x4{0.f, 0.f, 0.f, 0.f};

    for (int k0 = 0; k0 < 1024; k0 += 64) {
        __syncthreads();
        #pragma unroll
        for (int it = 0; it < 4; ++it) {
            int idx = it * 256 + tid;
            gload16(&As[idx * 8], A + (size_t)(m0 + (idx >> 3)) * 1024 + k0 + (idx & 7) * 8);
        }
        #pragma unroll
        for (int it = 0; it < 2; ++it) {
            int idx = it * 256 + tid;
            gload16(&Bs[idx * 8], Bt + (size_t)(n0 + (idx >> 3)) * 1024 + k0 + (idx & 7) * 8);
        }
        __syncthreads();
        #pragma unroll
        for (int kk = 0; kk < 2; ++kk) {
            const int krd = kk * 32 + hi * 8;
            bf16x8 af[4], bfr[2];
            #pragma unroll
            for (int i = 0; i < 4; ++i)
                af[i] = *(const bf16x8*)&As[(wm * 64 + i * 16 + l15) * 64 + krd];
            #pragma unroll
            for (int j = 0; j < 2; ++j)
                bfr[j] = *(const bf16x8*)&Bs[(wn * 32 + j * 16 + l15) * 64 + krd];
            #pragma unroll
            for (int i = 0; i < 4; ++i)
                #pragma unroll
                for (int j = 0; j < 2; ++j)
                    acc[i][j] = __builtin_amdgcn_mfma_f32_16x16x32_bf16(af[i], bfr[j], acc[i][j], 0, 0, 0);
        }
    }

    #pragma unroll
    for (int i = 0; i < 4; ++i)
        #pragma unroll
        for (int j = 0; j < 2; ++j) {
            int col = n0 + wn * 32 + j * 16 + l15;
            float bb1 = b1 ? b1[col] : 0.f;
            float bb2 = b2 ? b2[col] : 0.f;
            #pragma unroll
            for (int r = 0; r < 4; ++r) {
                int lrow = wm * 64 + i * 16 + hi * 4 + r;
                float v = acc[i][j][r];
                if (MODE == 1) {
                    size_t o = ((size_t)(nn_blk * 16 + (col >> 6)) * LROWS + lrbase + lrow) * 64 + (col & 63);
                    O1[o] = f2bf(v + bb1);
                    if (O2) O2[o] = f2bf(v + bb2);
                } else {
                    int row = m0 + lrow;
                    int nn = row >> 10, rr = row & 1023;
                    O1[((size_t)(nn * 16 + (col >> 6)) * 64 + (col & 63)) * 1024 + rr] = f2bf(v);
                }
            }
        }
}

// ---------------- merged output projection, tile 128m x 64n (R6 config) + XCD swizzle ----------------
// Bijective (nwg=320=8*40), y-major: each XCD owns contiguous y-panels with all x.
__global__ __launch_bounds__(256) void oproj(
    const ushort* __restrict__ AOc, const ushort* __restrict__ AOq,
    const ushort* __restrict__ Wo_t, float* __restrict__ out)
{
    __shared__ ushort As[128 * 64];
    __shared__ ushort Bs[64 * 64];

    int wg = blockIdx.x + 16 * blockIdx.y;
    int swz = (wg & 7) * 40 + (wg >> 3);
    const int y = swz >> 4;
    const int xx = swz & 15;

    const ushort* A;
    float* C;
    int m0;
    if (y < 16) { A = AOc; C = out; m0 = y * 128; }
    else        { A = AOq; C = out + (size_t)B_ * Q_ * 1024; m0 = (y - 16) * 128; }

    const int tid = threadIdx.x;
    const int lane = tid & 63, wave = tid >> 6;
    const int l15 = lane & 15, hi = lane >> 4;
    const int wm = wave >> 1, wn = wave & 1;
    const int n0 = xx * 64;

    f32x4 acc[4][2];
    #pragma unroll
    for (int i = 0; i < 4; ++i)
        #pragma unroll
        for (int j = 0; j < 2; ++j) acc[i][j] = f32x4{0.f, 0.f, 0.f, 0.f};

    for (int k0 = 0; k0 < 1024; k0 += 64) {
        __syncthreads();
        #pragma unroll
        for (int it = 0; it < 4; ++it) {
            int idx = it * 256 + tid;
            gload16(&As[idx * 8], A + (size_t)(m0 + (idx >> 3)) * 1024 + k0 + (idx & 7) * 8);
        }
        #pragma unroll
        for (int it = 0; it < 2; ++it) {
            int idx = it * 256 + tid;
            gload16(&Bs[idx * 8], Wo_t + (size_t)(n0 + (idx >> 3)) * 1024 + k0 + (idx & 7) * 8);
        }
        __syncthreads();
        #pragma unroll
        for (int kk = 0; kk < 2; ++kk) {
            const int krd = kk * 32 + hi * 8;
            bf16x8 af[4], bfr[2];
            #pragma unroll
            for (int i = 0; i < 4; ++i)
                af[i] = *(const bf16x8*)&As[(wm * 64 + i * 16 + l15) * 64 + krd];
            #pragma unroll
            for (int j = 0; j < 2; ++j)
                bfr[j] = *(const bf16x8*)&Bs[(wn * 32 + j * 16 + l15) * 64 + krd];
            #pragma unroll
            for (int i = 0; i < 4; ++i)
                #pragma unroll
                for (int j = 0; j < 2; ++j)
                    acc[i][j] = __builtin_amdgcn_mfma_f32_16x16x32_bf16(af[i], bfr[j], acc[i][j], 0, 0, 0);
        }
    }
    #pragma unroll
    for (int i = 0; i < 4; ++i)
        #pragma unroll
        for (int j = 0; j < 2; ++j) {
            int col = n0 + wn * 32 + j * 16 + l15;
            #pragma unroll
            for (int r = 0; r < 4; ++r) {
                int row = m0 + wm * 64 + i * 16 + hi * 4 + r;
                C[(size_t)row * 1024 + col] = acc[i][j][r];
            }
        }
}

// ---------------- PA gemm (query stream pos logits only) + XCD swizzle ----------------
// Bijective (nwg=768=8*96), nh-major: each XCD owns 8 nh values with all jt-blocks,
// so each KP panel (192 KB) stays in one per-XCD L2.
__global__ __launch_bounds__(256) void pa_gemm(const ushort* __restrict__ Qpb,
                                               const ushort* __restrict__ KPb,
                                               ushort* __restrict__ PA) {
    const int tid = threadIdx.x;
    const int lane = tid & 63, w = tid >> 6;
    const int l15 = lane & 15, hi = lane >> 4;

    int wg = blockIdx.x + 12 * blockIdx.y;
    int swz = (wg & 7) * 96 + (wg >> 3);
    const int nh = swz / 12;
    const int jt = (swz % 12) * 128;
    const int p0 = w * 32;

    bf16x8 a[2][2];
    #pragma unroll
    for (int i = 0; i < 2; ++i)
        #pragma unroll
        for (int kk = 0; kk < 2; ++kk)
            a[i][kk] = *(const bf16x8*)(Qpb + ((size_t)(nh * 128 + p0 + i * 16 + l15)) * 64 + kk * 32 + hi * 8);

    #pragma unroll
    for (int jc = 0; jc < 8; ++jc) {
        f32x4 c0 = {0.f,0.f,0.f,0.f}, c1 = {0.f,0.f,0.f,0.f};
        #pragma unroll
        for (int kk = 0; kk < 2; ++kk) {
            bf16x8 b = *(const bf16x8*)(KPb + ((size_t)nh * 1536 + jt + jc * 16 + l15) * 64 + kk * 32 + hi * 8);
            c0 = __builtin_amdgcn_mfma_f32_16x16x32_bf16(a[0][kk], b, c0, 0, 0, 0);
            c1 = __builtin_amdgcn_mfma_f32_16x16x32_bf16(a[1][kk], b, c1, 0, 0, 0);
        }
        #pragma unroll
        for (int r = 0; r < 4; ++r) {
            PA[((size_t)(nh * 128 + p0 + hi * 4 + r)) * 1536 + jt + jc * 16 + l15] = f2bf(c0[r]);
            PA[((size_t)(nh * 128 + p0 + 16 + hi * 4 + r)) * 1536 + jt + jc * 16 + l15] = f2bf(c1[r]);
        }
    }
}

// ---------------- barrier-free MFMA flash attention, 16 q-rows/wave, r-split 2 ----------------
// THE MEASURED OPTIMUM (R17/R20/R22 bench: ~119 us, VGPR 128 -> 4 waves/SIMD).
// grid (40, 32, 4), XCD-swizzled with L2-sized order bx -> part -> h -> n (per-XCD
// working set 3.6 MB <= 4 MB L2). bx<32 content (q0=bx*16); bx>=32 query.
// Phased loads: {kf+pseg} -> QK -> {kpf batch -> posMFMA | pav} -> {vf} -> softmax -> PV.
// Do NOT batch more loads into phase 1: R18 (+vf) and R19 (+kpf) both hit 144 VGPR
// -> 3 waves/SIMD and regressed. r-split 4 (R21) was a wash. No __syncthreads.
#define EXSC 0.180336879f
#define EXBI -23.0831204f
__global__ __launch_bounds__(64) void attn_uni(
    const ushort* __restrict__ Qccb, const ushort* __restrict__ Qcpb,
    const ushort* __restrict__ Qqcb,
    const ushort* __restrict__ KCb,  const ushort* __restrict__ KPb,
    const ushort* __restrict__ Vtb,  const ushort* __restrict__ segb,
    const float* __restrict__ segc,  const u64* __restrict__ pseg,
    const int* __restrict__ tpos,    const ushort* __restrict__ PA,
    float* __restrict__ Pp)
{
    __shared__ float Dlf[80 * 20];
    __shared__ ushort Pl[16 * 64];

    const int lane = threadIdx.x;
    const int l15 = lane & 15, hi = lane >> 4;

    // bijective XCD swizzle (nwg=5120), L2-sized logical order bx -> part -> h -> n
    int wg = blockIdx.x + 40 * (blockIdx.y + 32 * blockIdx.z);
    int swz = (wg & 7) * 640 + (wg >> 3);
    const int bx = swz % 40;
    int rem = swz / 40;          // 0..127
    const int part = rem & 1;
    int rem2 = rem >> 1;         // 0..63
    const int h = rem2 & 15;
    const int n = rem2 >> 4;

    const bool ISQ = bx >= 32;
    const int nh = n * 16 + h;
    const int q0w = (ISQ ? (bx - 32) : bx) * 16;

    // hoisted Q fragments (16 rows)
    bf16x8 acb[2], apb[2];
    {
        const ushort* qc = ISQ ? (Qqcb + ((size_t)nh * P_ + q0w) * 64)
                               : (Qccb + ((size_t)nh * Q_ + q0w) * 64);
        #pragma unroll
        for (int kk = 0; kk < 2; ++kk)
            acb[kk] = *(const bf16x8*)(qc + (size_t)l15 * 64 + kk * 32 + hi * 8);
        if (!ISQ) {
            const ushort* qp = Qcpb + ((size_t)nh * Q_ + q0w) * 64;
            #pragma unroll
            for (int kk = 0; kk < 2; ++kk)
                apb[kk] = *(const bf16x8*)(qp + (size_t)l15 * 64 + kk * 32 + hi * 8);
        } else {
            apb[0] = acb[0]; apb[1] = acb[1];
        }
    }

    // segment logits via MFMA + bpermute broadcast
    float sd[2][4];
    {
        f32x4 sg = {0.f, 0.f, 0.f, 0.f};
        #pragma unroll
        for (int kk = 0; kk < 2; ++kk) {
            bf16x8 b = *(const bf16x8*)(segb + (size_t)(h * 16 + l15) * 64 + kk * 32 + hi * 8);
            sg = __builtin_amdgcn_mfma_f32_16x16x32_bf16(acb[kk], b, sg, 0, 0, 0);
        }
        float c0 = segc[h * 2 + 0], c1 = segc[h * 2 + 1];
        #pragma unroll
        for (int r = 0; r < 4; ++r) {
            int base = (lane & 48) << 2;
            sd[0][r] = __int_as_float(__builtin_amdgcn_ds_bpermute(base, __float_as_int(sg[r]))) + c0;
            sd[1][r] = __int_as_float(__builtin_amdgcn_ds_bpermute(base + 4, __float_as_int(sg[r]))) + c1;
        }
    }

    int qg[4];
    #pragma unroll
    for (int r = 0; r < 4; ++r) {
        int p = q0w + hi * 4 + r;
        qg[r] = ISQ ? tpos[n * P_ + p] : p;
    }

    f32x4 acc[4];
    float psum[4] = {};
    #pragma unroll
    for (int j = 0; j < 4; ++j) acc[j] = f32x4{0.f, 0.f, 0.f, 0.f};

    // even r-split 2 over this wave's exact causal range
    const int ntb = ISQ ? 16 : (((q0w + 527) >> 6) + 1);
    const int nt1 = (ntb + 1) >> 1;
    const int t0 = part ? nt1 : 0;
    const int tmax = part ? ntb : nt1;

    for (int rt = t0; rt < tmax; ++rt) {
        const int r0 = rt * 64;

        // ---- phase 1: K fragments + pseg (batched) ----
        bf16x8 kf[2][4];
        #pragma unroll
        for (int kk = 0; kk < 2; ++kk)
            #pragma unroll
            for (int fc = 0; fc < 4; ++fc)
                kf[kk][fc] = *(const bf16x8*)(KCb + ((size_t)nh * R_ + r0 + fc * 16 + l15) * 64 + kk * 32 + hi * 8);
        u64 sw[4];
        #pragma unroll
        for (int r = 0; r < 4; ++r)
            sw[r] = pseg[((size_t)n * Q_ + qg[r]) * 16 + rt];

        // ---- QK^T (16q x 64r) ----
        f32x4 s[4];
        #pragma unroll
        for (int fc = 0; fc < 4; ++fc) s[fc] = f32x4{0.f, 0.f, 0.f, 0.f};
        #pragma unroll
        for (int kk = 0; kk < 2; ++kk)
            #pragma unroll
            for (int fc = 0; fc < 4; ++fc)
                s[fc] = __builtin_amdgcn_mfma_f32_16x16x32_bf16(acb[kk], kf[kk][fc], s[fc], 0, 0, 0);

        // ---- phase 2: KP band (content) / PA gather (query); kf registers dead ----
        if (!ISQ) {
            const int jb0 = r0 - q0w + 497;   // 80 rows cover j = r - q + 512
            bf16x8 kpf[5][2];
            #pragma unroll
            for (int t = 0; t < 5; ++t)
                #pragma unroll
                for (int kk = 0; kk < 2; ++kk)
                    kpf[t][kk] = *(const bf16x8*)(KPb + ((size_t)nh * POSLEN_ + jb0 + t * 16 + l15) * 64 + kk * 32 + hi * 8);
            #pragma unroll
            for (int t = 0; t < 5; ++t) {
                f32x4 d0 = {0.f, 0.f, 0.f, 0.f};
                #pragma unroll
                for (int kk = 0; kk < 2; ++kk)
                    d0 = __builtin_amdgcn_mfma_f32_16x16x32_bf16(apb[kk], kpf[t][kk], d0, 0, 0, 0);
                *(f32x4*)(&Dlf[(t * 16 + l15) * 20 + hi * 4]) = d0;
            }
        }
        float pav[4][4];
        if (ISQ) {
            #pragma unroll
            for (int fc = 0; fc < 4; ++fc)
                #pragma unroll
                for (int r = 0; r < 4; ++r) {
                    int qq = hi * 4 + r;
                    int j = (r0 + fc * 16 + l15) - qg[r] + 512;
                    pav[fc][r] = bf2f(PA[((size_t)nh * P_ + q0w + qq) * 1536 + j]);
                }
        }

        // ---- phase 3: V fragments issued BEFORE softmax (latency hides under exp chain) ----
        bf16x8 vf[2][4];
        #pragma unroll
        for (int kk = 0; kk < 2; ++kk)
            #pragma unroll
            for (int dj = 0; dj < 4; ++dj)
                vf[kk][dj] = *(const bf16x8*)(Vtb + ((size_t)nh * 64 + dj * 16 + l15) * 1024 + r0 + kk * 32 + hi * 8);

        // ---- fixed-max softmax: p = 2^(s_tot*EXSC + EXBI) ----
        #pragma unroll
        for (int fc = 0; fc < 4; ++fc) {
            #pragma unroll
            for (int r = 0; r < 4; ++r) {
                int qq = hi * 4 + r;
                int rr = fc * 16 + l15;
                float dval = ISQ ? pav[fc][r] : Dlf[(rr - qq + 15) * 20 + qq];
                int sel = (int)((sw[r] >> rr) & 1);
                float st = s[fc][r] + dval + (sel ? sd[1][r] : sd[0][r]);
                float v = fmaf(st, EXSC, EXBI);
                bool masked = (r0 + rr) >= qg[r] + (ISQ ? 512 : 513);
                v = masked ? -INFINITY : v;
                float pv = exp2f(v);
                ushort us = f2bf(pv);
                psum[r] += bf2f(us);
                int row = hi * 4 + r;
                int cc = rr ^ ((row & 7) << 3);
                Pl[row * 64 + cc] = us;
            }
        }

        // ---- PV ----
        #pragma unroll
        for (int kk = 0; kk < 2; ++kk) {
            int cc = (kk * 32 + hi * 8) ^ ((l15 & 7) << 3);
            bf16x8 pa = *(const bf16x8*)&Pl[l15 * 64 + cc];
            #pragma unroll
            for (int dj = 0; dj < 4; ++dj)
                acc[dj] = __builtin_amdgcn_mfma_f32_16x16x32_bf16(pa, vf[kk][dj], acc[dj], 0, 0, 0);
        }
    }

    // final psum reduce over the 16 column-lanes
    #pragma unroll
    for (int r = 0; r < 4; ++r) {
        #pragma unroll
        for (int d = 1; d < 16; d <<= 1) psum[r] += __shfl_xor(psum[r], d, 64);
    }

    // write partials (2 parts per row)
    #pragma unroll
    for (int r = 0; r < 4; ++r) {
        int qrow = q0w + hi * 4 + r;
        size_t rowg = ISQ ? (32768 + (size_t)nh * P_ + qrow) : ((size_t)nh * Q_ + qrow);
        float* base = Pp + (rowg * 2 + part) * 72;
        #pragma unroll
        for (int dj = 0; dj < 4; ++dj)
            base[dj * 16 + l15] = acc[dj][r];
        if (l15 == 0) base[64] = psum[r];
    }
}

// combine r-split partials (2 parts)
__global__ __launch_bounds__(256) void combine_k(const float* __restrict__ Pp,
                                                 ushort* __restrict__ AOc,
                                                 ushort* __restrict__ AOq) {
    int idx = blockIdx.x * 256 + threadIdx.x;
    int row = idx >> 6, d = idx & 63;
    const float* b0 = Pp + ((size_t)row * 2 + 0) * 72;
    const float* b1 = b0 + 72;
    float l = b0[64] + b1[64];
    ushort o = f2bf((b0[d] + b1[d]) / l);
    if (row < 32768) {
        int n = row >> 13, h = (row >> 9) & 15, q = row & 511;
        AOc[((size_t)(n * Q_ + q)) * 1024 + h * 64 + d] = o;
    } else {
        int r2 = row - 32768;
        int n = r2 >> 11, h = (r2 >> 7) & 15, p = r2 & 127;
        AOq[((size_t)(n * P_ + p)) * 1024 + h * 64 + d] = o;
    }
}

extern "C" void kernel_launch(void* const* d_in, const int* in_sizes, int n_in,
                              void* d_out, int out_size, void* d_ws, size_t ws_size,
                              hipStream_t stream) {
    const float* content = (const float*)d_in[0];
    const float* query   = (const float*)d_in[1];
    const float* posenc  = (const float*)d_in[2];
    const float* segenc  = (const float*)d_in[3];
    const int*   segmat  = (const int*)d_in[4];
    const float* tmap    = (const float*)d_in[5];
    const float* cbias   = (const float*)d_in[8];
    const float* pbias   = (const float*)d_in[9];
    const float* sbias   = (const float*)d_in[10];
    const float* mems    = (const float*)d_in[11];
    const float* Wq      = (const float*)d_in[12];
    const float* Wkc     = (const float*)d_in[13];
    const float* Wv      = (const float*)d_in[14];
    const float* Wkp     = (const float*)d_in[15];
    const float* Wo      = (const float*)d_in[16];
    float* out = (float*)d_out;

    char* p = (char*)d_ws;
    auto alloc = [&](size_t bytes) { char* r = p; p += (bytes + 255) & ~(size_t)255; return r; };
    ushort* ctx_bf  = (ushort*)alloc((size_t)B_ * R_ * 1024 * 2);
    ushort* pos_bf  = (ushort*)alloc((size_t)B_ * POSLEN_ * 1024 * 2);
    ushort* qry_bf  = (ushort*)alloc((size_t)B_ * P_ * 1024 * 2);
    ushort* Wq_t    = (ushort*)alloc(1024 * 1024 * 2);
    ushort* Wkc_t   = (ushort*)alloc(1024 * 1024 * 2);
    ushort* Wv_t    = (ushort*)alloc(1024 * 1024 * 2);
    ushort* Wkp_t   = (ushort*)alloc(1024 * 1024 * 2);
    ushort* Wo_t    = (ushort*)alloc(1024 * 1024 * 2);
    ushort* KC_bf   = (ushort*)alloc((size_t)B_ * 16 * R_ * 64 * 2);
    ushort* Vt_bf   = (ushort*)alloc((size_t)B_ * 16 * 64 * R_ * 2);
    ushort* KP_bf   = (ushort*)alloc((size_t)B_ * 16 * POSLEN_ * 64 * 2);
    ushort* Qc_cb   = (ushort*)alloc((size_t)B_ * 16 * Q_ * 64 * 2);
    ushort* Qc_pb   = (ushort*)alloc((size_t)B_ * 16 * Q_ * 64 * 2);
    ushort* Qq_cb   = (ushort*)alloc((size_t)B_ * 16 * P_ * 64 * 2);
    ushort* Qq_pb   = (ushort*)alloc((size_t)B_ * 16 * P_ * 64 * 2);
    ushort* PAq_bf  = (ushort*)alloc((size_t)B_ * 16 * P_ * 1536 * 2);
    ushort* AOc_bf  = (ushort*)alloc((size_t)B_ * Q_ * 1024 * 2);
    ushort* AOq_bf  = (ushort*)alloc((size_t)B_ * P_ * 1024 * 2);
    ushort* seg_bf  = (ushort*)alloc(16 * 16 * 64 * 2);
    float*  segc    = (float*)alloc(32 * 4);
    u64*    pseg    = (u64*)alloc((size_t)B_ * Q_ * 16 * 8);
    int*    tpos    = (int*)alloc(B_ * P_ * 4);
    // DEDICATED r-split partials buffer: 40960 rows x 2 parts x 72 f32 = 23.6 MB.
    float* Pp = (float*)alloc((size_t)40960 * 2 * 72 * 4);

    // merged prep (one dispatch; content is read via ctx_bf, no separate copy)
    prep_all<<<18691, 256, 0, stream>>>(content, mems, posenc, query,
                                        ctx_bf, pos_bf, qry_bf,
                                        Wq, Wkc, Wv, Wkp, Wo,
                                        Wq_t, Wkc_t, Wv_t, Wkp_t, Wo_t,
                                        segmat, pseg,
                                        segenc, cbias, sbias, seg_bf, segc,
                                        tmap, tpos);

    // all projections, one dispatch (128x64 tiles, XCD-swizzled y-major)
    proj_all<<<dim3(16, 132), 256, 0, stream>>>(ctx_bf, pos_bf, qry_bf,
                                                Wkc_t, Wv_t, Wkp_t, Wq_t,
                                                KC_bf, Vt_bf, KP_bf,
                                                Qc_cb, Qc_pb, Qq_cb, Qq_pb,
                                                cbias, pbias);

    // query-stream shifted pos logits (XCD-swizzled nh-major)
    pa_gemm<<<dim3(12, 64), 256, 0, stream>>>(Qq_pb, KP_bf, PAq_bf);

    // barrier-free fused attention (measured optimum), L2-sized swizzle
    attn_uni<<<dim3(40, 32, 4), 64, 0, stream>>>(Qc_cb, Qc_pb, Qq_cb, KC_bf, KP_bf, Vt_bf,
                                                 seg_bf, segc, pseg, tpos, PAq_bf, Pp);

    // combine partials -> bf16 AO
    combine_k<<<10240, 256, 0, stream>>>(Pp, AOc_bf, AOq_bf);

    // output projection, one dispatch (128x64 tiles, XCD-swizzled y-major)
    oproj<<<dim3(16, 20), 256, 0, stream>>>(AOc_bf, AOq_bf, Wo_t, out);

    (void)in_sizes; (void)n_in; (void)out_size; (void)ws_size;
}

// Round 24
// 258.814 us; speedup vs baseline: 1.0239x; 1.0239x over previous
//
#include <hip/hip_runtime.h>
#include <hip/hip_bf16.h>
#include <math.h>

#define B_ 4
#define Q_ 512
#define M_ 512
#define P_ 128
#define HID_ 1024
#define H_ 16
#define S_ 64
#define R_ 1024
#define POSLEN_ 1536

typedef short bf16x8 __attribute__((ext_vector_type(8)));
typedef float f32x4 __attribute__((ext_vector_type(4)));
typedef unsigned int u32;
typedef unsigned long long u64;

__device__ __forceinline__ ushort f2bf(float f) {
    u32 u = __float_as_uint(f);
    u32 r = (u + 0x7fffu + ((u >> 16) & 1u)) >> 16;
    return (ushort)r;
}
__device__ __forceinline__ float bf2f(ushort s) {
    return __uint_as_float(((u32)s) << 16);
}
__device__ __forceinline__ void gload16(void* l, const void* g) {
    __builtin_amdgcn_global_load_lds(
        (const __attribute__((address_space(1))) u32*)g,
        (__attribute__((address_space(3))) u32*)l, 16, 0, 0);
}

// ---------------- merged prep kernel: cvt + transpose5 + pack_seg + seg_prep + find_tpos ----------------
// Block ranges: [0,5376) cvt (ctx|posenc|query; content read from ctx_bf rows 512..)
// | [5376,10496) transpose | [10496,18688) pack_seg | 18688 seg_prep | [18689,18691) find_tpos.
__global__ __launch_bounds__(256) void prep_all(
    const float* __restrict__ content, const float* __restrict__ mems,
    const float* __restrict__ posenc,  const float* __restrict__ query,
    ushort* __restrict__ ctx, ushort* __restrict__ pos,
    ushort* __restrict__ qry,
    const float* W0, const float* W1, const float* W2, const float* W3, const float* W4,
    ushort* T0, ushort* T1, ushort* T2, ushort* T3, ushort* T4,
    const int* __restrict__ seg, u64* __restrict__ psego,
    const float* __restrict__ segenc, const float* __restrict__ cb,
    const float* __restrict__ sb, ushort* __restrict__ seg_bf,
    float* __restrict__ segc,
    const float* __restrict__ tm, int* __restrict__ tpos)
{
    __shared__ float t[32][33];
    const int bid = blockIdx.x;
    const int tid = threadIdx.x;

    if (bid < 5376) {
        int v = bid * 256 + tid;
        const float* src;
        ushort* dst;
        if (v < 524288) {
            int row = v >> 7, c8 = v & 127;
            int n = row >> 10, l = row & 1023;
            src = (l < M_) ? mems + ((size_t)(n * M_ + l)) * 1024 + c8 * 8
                           : content + ((size_t)(n * Q_ + (l - M_))) * 1024 + c8 * 8;
            dst = ctx + (size_t)v * 8;
        } else if (v < 1310720) {
            int u = v - 524288;
            src = posenc + (size_t)u * 8; dst = pos + (size_t)u * 8;
        } else {
            int u = v - 1310720;
            src = query + (size_t)u * 8; dst = qry + (size_t)u * 8;
        }
        float4 a = *(const float4*)src;
        float4 b = *(const float4*)(src + 4);
        ushort4 o0 = {f2bf(a.x), f2bf(a.y), f2bf(a.z), f2bf(a.w)};
        ushort4 o1 = {f2bf(b.x), f2bf(b.y), f2bf(b.z), f2bf(b.w)};
        *(ushort4*)dst = o0;
        *(ushort4*)(dst + 4) = o1;
    } else if (bid < 10496) {
        int b2 = bid - 5376;
        int bxw = (b2 & 31) * 32;
        int byw = ((b2 >> 5) & 31) * 32;
        int z = b2 >> 10;
        const float* W; ushort* T;
        switch (z) {
            case 0: W = W0; T = T0; break;
            case 1: W = W1; T = T1; break;
            case 2: W = W2; T = T2; break;
            case 3: W = W3; T = T3; break;
            default: W = W4; T = T4; break;
        }
        int tx = tid & 31, ty = tid >> 5;
        #pragma unroll
        for (int i = 0; i < 32; i += 8)
            t[ty + i][tx] = W[(size_t)(byw + ty + i) * 1024 + bxw + tx];
        __syncthreads();
        #pragma unroll
        for (int i = 0; i < 32; i += 8)
            T[(size_t)(bxw + ty + i) * 1024 + byw + tx] = f2bf(t[tx][ty + i]);
    } else if (bid < 18688) {
        int idx = (bid - 10496) * 256 + tid;
        u64 m = __ballot(seg[idx] > 0);
        if ((tid & 63) == 0) psego[idx >> 6] = m;
    } else if (bid == 18688) {
        for (int tt = tid; tt < 16 * 16 * 64; tt += 256) {
            int h = tt >> 10, g = (tt >> 6) & 15, s = tt & 63;
            float v = (g < 2) ? segenc[(size_t)(g * 16 + h) * 64 + s] : 0.f;
            seg_bf[tt] = f2bf(v);
        }
        if (tid < 32) {
            int h = tid >> 1, g = tid & 1;
            float acc = 0.f;
            for (int s = 0; s < 64; ++s)
                acc += (sb[h * 64 + s] - cb[h * 64 + s]) * segenc[(size_t)(g * 16 + h) * 64 + s];
            segc[h * 2 + g] = acc;
        }
    } else {
        int i = (bid - 18689) * 256 + tid;
        if (i < B_ * P_) {
            const float* row = tm + (size_t)i * Q_;
            int q = 0;
            for (int j = 0; j < Q_; ++j) q = (row[j] > 0.5f) ? j : q;
            tpos[i] = q;
        }
    }
}

// ---------------- merged projection GEMM, tile 128m x 64n (R6 config) ----------------
// Qc jobs (y in [112,128)) read A from ctx_bf rows 512.. of each batch (content region).
__global__ __launch_bounds__(256) void proj_all(
    const ushort* __restrict__ ctx, const ushort* __restrict__ pos,
    const ushort* __restrict__ qry,
    const ushort* __restrict__ Wkc_t, const ushort* __restrict__ Wv_t,
    const ushort* __restrict__ Wkp_t, const ushort* __restrict__ Wq_t,
    ushort* __restrict__ KC, ushort* __restrict__ Vt, ushort* __restrict__ KP,
    ushort* __restrict__ Qccb, ushort* __restrict__ Qcpb,
    ushort* __restrict__ Qqcb, ushort* __restrict__ Qqpb,
    const float* __restrict__ cbias, const float* __restrict__ pbias)
{
    __shared__ ushort As[128 * 64];
    __shared__ ushort Bs[64 * 64];
    const int y = blockIdx.y;
    const ushort *A, *Bt;
    ushort *O1, *O2 = nullptr;
    const float *b1 = nullptr, *b2 = nullptr;
    int LROWS, MODE, m0;
    if (y < 32)       { A = ctx;  Bt = Wkc_t; O1 = KC;   LROWS = 1024; MODE = 1; m0 = y * 128; }
    else if (y < 64)  { A = ctx;  Bt = Wv_t;  O1 = Vt;   LROWS = 1024; MODE = 2; m0 = (y - 32) * 128; }
    else if (y < 112) { A = pos;  Bt = Wkp_t; O1 = KP;   LROWS = 1536; MODE = 1; m0 = (y - 64) * 128; }
    else if (y < 128) {
        // content Q projection: A rows live inside ctx at n*1024 + 512 + l
        A = ctx + ((size_t)((((y - 112) >> 2) * 512) + 512) * 1024);
        Bt = Wq_t;  O1 = Qccb; O2 = Qcpb; b1 = cbias; b2 = pbias; LROWS = 512; MODE = 1; m0 = (y - 112) * 128;
    }
    else              { A = qry;  Bt = Wq_t;  O1 = Qqcb; O2 = Qqpb; b1 = cbias; b2 = pbias; LROWS = 128; MODE = 1; m0 = (y - 128) * 128; }
    const int nn_blk = m0 / LROWS;
    const int lrbase = m0 - nn_blk * LROWS;

    const int tid = threadIdx.x;
    const int lane = tid & 63, wave = tid >> 6;
    const int l15 = lane & 15, hi = lane >> 4;
    const int wm = wave >> 1, wn = wave & 1;
    const int n0 = blockIdx.x * 64;

    f32x4 acc[4][2];
    #pragma unroll
    for (int i = 0; i < 4; ++i)
        #pragma unroll
        for (int j = 0; j < 2; ++j) acc[i][j] = f32x4{0.f, 0.f, 0.f, 0.f};

    for (int k0 = 0; k0 < 1024; k0 += 64) {
        __syncthreads();
        #pragma unroll
        for (int it = 0; it < 4; ++it) {
            int idx = it * 256 + tid;
            gload16(&As[idx * 8], A + (size_t)(m0 + (idx >> 3)) * 1024 + k0 + (idx & 7) * 8);
        }
        #pragma unroll
        for (int it = 0; it < 2; ++it) {
            int idx = it * 256 + tid;
            gload16(&Bs[idx * 8], Bt + (size_t)(n0 + (idx >> 3)) * 1024 + k0 + (idx & 7) * 8);
        }
        __syncthreads();
        #pragma unroll
        for (int kk = 0; kk < 2; ++kk) {
            const int krd = kk * 32 + hi * 8;
            bf16x8 af[4], bfr[2];
            #pragma unroll
            for (int i = 0; i < 4; ++i)
                af[i] = *(const bf16x8*)&As[(wm * 64 + i * 16 + l15) * 64 + krd];
            #pragma unroll
            for (int j = 0; j < 2; ++j)
                bfr[j] = *(const bf16x8*)&Bs[(wn * 32 + j * 16 + l15) * 64 + krd];
            #pragma unroll
            for (int i = 0; i < 4; ++i)
                #pragma unroll
                for (int j = 0; j < 2; ++j)
                    acc[i][j] = __builtin_amdgcn_mfma_f32_16x16x32_bf16(af[i], bfr[j], acc[i][j], 0, 0, 0);
        }
    }

    #pragma unroll
    for (int i = 0; i < 4; ++i)
        #pragma unroll
        for (int j = 0; j < 2; ++j) {
            int col = n0 + wn * 32 + j * 16 + l15;
            float bb1 = b1 ? b1[col] : 0.f;
            float bb2 = b2 ? b2[col] : 0.f;
            #pragma unroll
            for (int r = 0; r < 4; ++r) {
                int lrow = wm * 64 + i * 16 + hi * 4 + r;
                float v = acc[i][j][r];
                if (MODE == 1) {
                    size_t o = ((size_t)(nn_blk * 16 + (col >> 6)) * LROWS + lrbase + lrow) * 64 + (col & 63);
                    O1[o] = f2bf(v + bb1);
                    if (O2) O2[o] = f2bf(v + bb2);
                } else {
                    int row = m0 + lrow;
                    int nn = row >> 10, rr = row & 1023;
                    O1[((size_t)(nn * 16 + (col >> 6)) * 64 + (col & 63)) * 1024 + rr] = f2bf(v);
                }
            }
        }
}

// ---------------- merged output projection, tile 128m x 64n (R6 config) ----------------
__global__ __launch_bounds__(256) void oproj(
    const ushort* __restrict__ AOc, const ushort* __restrict__ AOq,
    const ushort* __restrict__ Wo_t, float* __restrict__ out)
{
    __shared__ ushort As[128 * 64];
    __shared__ ushort Bs[64 * 64];
    const int y = blockIdx.y;
    const ushort* A;
    float* C;
    int m0;
    if (y < 16) { A = AOc; C = out; m0 = y * 128; }
    else        { A = AOq; C = out + (size_t)B_ * Q_ * 1024; m0 = (y - 16) * 128; }

    const int tid = threadIdx.x;
    const int lane = tid & 63, wave = tid >> 6;
    const int l15 = lane & 15, hi = lane >> 4;
    const int wm = wave >> 1, wn = wave & 1;
    const int n0 = blockIdx.x * 64;

    f32x4 acc[4][2];
    #pragma unroll
    for (int i = 0; i < 4; ++i)
        #pragma unroll
        for (int j = 0; j < 2; ++j) acc[i][j] = f32x4{0.f, 0.f, 0.f, 0.f};

    for (int k0 = 0; k0 < 1024; k0 += 64) {
        __syncthreads();
        #pragma unroll
        for (int it = 0; it < 4; ++it) {
            int idx = it * 256 + tid;
            gload16(&As[idx * 8], A + (size_t)(m0 + (idx >> 3)) * 1024 + k0 + (idx & 7) * 8);
        }
        #pragma unroll
        for (int it = 0; it < 2; ++it) {
            int idx = it * 256 + tid;
            gload16(&Bs[idx * 8], Wo_t + (size_t)(n0 + (idx >> 3)) * 1024 + k0 + (idx & 7) * 8);
        }
        __syncthreads();
        #pragma unroll
        for (int kk = 0; kk < 2; ++kk) {
            const int krd = kk * 32 + hi * 8;
            bf16x8 af[4], bfr[2];
            #pragma unroll
            for (int i = 0; i < 4; ++i)
                af[i] = *(const bf16x8*)&As[(wm * 64 + i * 16 + l15) * 64 + krd];
            #pragma unroll
            for (int j = 0; j < 2; ++j)
                bfr[j] = *(const bf16x8*)&Bs[(wn * 32 + j * 16 + l15) * 64 + krd];
            #pragma unroll
            for (int i = 0; i < 4; ++i)
                #pragma unroll
                for (int j = 0; j < 2; ++j)
                    acc[i][j] = __builtin_amdgcn_mfma_f32_16x16x32_bf16(af[i], bfr[j], acc[i][j], 0, 0, 0);
        }
    }
    #pragma unroll
    for (int i = 0; i < 4; ++i)
        #pragma unroll
        for (int j = 0; j < 2; ++j) {
            int col = n0 + wn * 32 + j * 16 + l15;
            #pragma unroll
            for (int r = 0; r < 4; ++r) {
                int row = m0 + wm * 64 + i * 16 + hi * 4 + r;
                C[(size_t)row * 1024 + col] = acc[i][j][r];
            }
        }
}

// ---------------- PA gemm (query stream pos logits only) ----------------
__global__ __launch_bounds__(256) void pa_gemm(const ushort* __restrict__ Qpb,
                                               const ushort* __restrict__ KPb,
                                               ushort* __restrict__ PA) {
    const int tid = threadIdx.x;
    const int lane = tid & 63, w = tid >> 6;
    const int l15 = lane & 15, hi = lane >> 4;
    const int jt = blockIdx.x * 128, nh = blockIdx.y;
    const int p0 = w * 32;

    bf16x8 a[2][2];
    #pragma unroll
    for (int i = 0; i < 2; ++i)
        #pragma unroll
        for (int kk = 0; kk < 2; ++kk)
            a[i][kk] = *(const bf16x8*)(Qpb + ((size_t)(nh * 128 + p0 + i * 16 + l15)) * 64 + kk * 32 + hi * 8);

    #pragma unroll
    for (int jc = 0; jc < 8; ++jc) {
        f32x4 c0 = {0.f,0.f,0.f,0.f}, c1 = {0.f,0.f,0.f,0.f};
        #pragma unroll
        for (int kk = 0; kk < 2; ++kk) {
            bf16x8 b = *(const bf16x8*)(KPb + ((size_t)nh * 1536 + jt + jc * 16 + l15) * 64 + kk * 32 + hi * 8);
            c0 = __builtin_amdgcn_mfma_f32_16x16x32_bf16(a[0][kk], b, c0, 0, 0, 0);
            c1 = __builtin_amdgcn_mfma_f32_16x16x32_bf16(a[1][kk], b, c1, 0, 0, 0);
        }
        #pragma unroll
        for (int r = 0; r < 4; ++r) {
            PA[((size_t)(nh * 128 + p0 + hi * 4 + r)) * 1536 + jt + jc * 16 + l15] = f2bf(c0[r]);
            PA[((size_t)(nh * 128 + p0 + 16 + hi * 4 + r)) * 1536 + jt + jc * 16 + l15] = f2bf(c1[r]);
        }
    }
}

// ---------------- barrier-free MFMA flash attention, 16 q-rows/wave, r-split 2 ----------------
// THE MEASURED OPTIMUM (R17/R20/R22 bench: ~119 us, VGPR 128 -> 4 waves/SIMD).
// grid (40, 32, 4), XCD-swizzled with L2-sized order bx -> part -> h -> n (per-XCD
// working set 3.6 MB <= 4 MB L2). bx<32 content (q0=bx*16); bx>=32 query.
// Phased loads: {kf+pseg} -> QK -> {kpf batch -> posMFMA | pav} -> {vf} -> softmax -> PV.
// Do NOT batch more loads into phase 1: R18 (+vf) and R19 (+kpf) both hit 144 VGPR
// -> 3 waves/SIMD and regressed. r-split 4 (R21) was a wash; projection XCD swizzle
// (R23) regressed (~+5 us, L3 already absorbed panel re-reads). No __syncthreads.
#define EXSC 0.180336879f
#define EXBI -23.0831204f
__global__ __launch_bounds__(64) void attn_uni(
    const ushort* __restrict__ Qccb, const ushort* __restrict__ Qcpb,
    const ushort* __restrict__ Qqcb,
    const ushort* __restrict__ KCb,  const ushort* __restrict__ KPb,
    const ushort* __restrict__ Vtb,  const ushort* __restrict__ segb,
    const float* __restrict__ segc,  const u64* __restrict__ pseg,
    const int* __restrict__ tpos,    const ushort* __restrict__ PA,
    float* __restrict__ Pp)
{
    __shared__ float Dlf[80 * 20];
    __shared__ ushort Pl[16 * 64];

    const int lane = threadIdx.x;
    const int l15 = lane & 15, hi = lane >> 4;

    // bijective XCD swizzle (nwg=5120), L2-sized logical order bx -> part -> h -> n
    int wg = blockIdx.x + 40 * (blockIdx.y + 32 * blockIdx.z);
    int swz = (wg & 7) * 640 + (wg >> 3);
    const int bx = swz % 40;
    int rem = swz / 40;          // 0..127
    const int part = rem & 1;
    int rem2 = rem >> 1;         // 0..63
    const int h = rem2 & 15;
    const int n = rem2 >> 4;

    const bool ISQ = bx >= 32;
    const int nh = n * 16 + h;
    const int q0w = (ISQ ? (bx - 32) : bx) * 16;

    // hoisted Q fragments (16 rows)
    bf16x8 acb[2], apb[2];
    {
        const ushort* qc = ISQ ? (Qqcb + ((size_t)nh * P_ + q0w) * 64)
                               : (Qccb + ((size_t)nh * Q_ + q0w) * 64);
        #pragma unroll
        for (int kk = 0; kk < 2; ++kk)
            acb[kk] = *(const bf16x8*)(qc + (size_t)l15 * 64 + kk * 32 + hi * 8);
        if (!ISQ) {
            const ushort* qp = Qcpb + ((size_t)nh * Q_ + q0w) * 64;
            #pragma unroll
            for (int kk = 0; kk < 2; ++kk)
                apb[kk] = *(const bf16x8*)(qp + (size_t)l15 * 64 + kk * 32 + hi * 8);
        } else {
            apb[0] = acb[0]; apb[1] = acb[1];
        }
    }

    // segment logits via MFMA + bpermute broadcast
    float sd[2][4];
    {
        f32x4 sg = {0.f, 0.f, 0.f, 0.f};
        #pragma unroll
        for (int kk = 0; kk < 2; ++kk) {
            bf16x8 b = *(const bf16x8*)(segb + (size_t)(h * 16 + l15) * 64 + kk * 32 + hi * 8);
            sg = __builtin_amdgcn_mfma_f32_16x16x32_bf16(acb[kk], b, sg, 0, 0, 0);
        }
        float c0 = segc[h * 2 + 0], c1 = segc[h * 2 + 1];
        #pragma unroll
        for (int r = 0; r < 4; ++r) {
            int base = (lane & 48) << 2;
            sd[0][r] = __int_as_float(__builtin_amdgcn_ds_bpermute(base, __float_as_int(sg[r]))) + c0;
            sd[1][r] = __int_as_float(__builtin_amdgcn_ds_bpermute(base + 4, __float_as_int(sg[r]))) + c1;
        }
    }

    int qg[4];
    #pragma unroll
    for (int r = 0; r < 4; ++r) {
        int p = q0w + hi * 4 + r;
        qg[r] = ISQ ? tpos[n * P_ + p] : p;
    }

    f32x4 acc[4];
    float psum[4] = {};
    #pragma unroll
    for (int j = 0; j < 4; ++j) acc[j] = f32x4{0.f, 0.f, 0.f, 0.f};

    // even r-split 2 over this wave's exact causal range
    const int ntb = ISQ ? 16 : (((q0w + 527) >> 6) + 1);
    const int nt1 = (ntb + 1) >> 1;
    const int t0 = part ? nt1 : 0;
    const int tmax = part ? ntb : nt1;

    for (int rt = t0; rt < tmax; ++rt) {
        const int r0 = rt * 64;

        // ---- phase 1: K fragments + pseg (batched) ----
        bf16x8 kf[2][4];
        #pragma unroll
        for (int kk = 0; kk < 2; ++kk)
            #pragma unroll
            for (int fc = 0; fc < 4; ++fc)
                kf[kk][fc] = *(const bf16x8*)(KCb + ((size_t)nh * R_ + r0 + fc * 16 + l15) * 64 + kk * 32 + hi * 8);
        u64 sw[4];
        #pragma unroll
        for (int r = 0; r < 4; ++r)
            sw[r] = pseg[((size_t)n * Q_ + qg[r]) * 16 + rt];

        // ---- QK^T (16q x 64r) ----
        f32x4 s[4];
        #pragma unroll
        for (int fc = 0; fc < 4; ++fc) s[fc] = f32x4{0.f, 0.f, 0.f, 0.f};
        #pragma unroll
        for (int kk = 0; kk < 2; ++kk)
            #pragma unroll
            for (int fc = 0; fc < 4; ++fc)
                s[fc] = __builtin_amdgcn_mfma_f32_16x16x32_bf16(acb[kk], kf[kk][fc], s[fc], 0, 0, 0);

        // ---- phase 2: KP band (content) / PA gather (query); kf registers dead ----
        if (!ISQ) {
            const int jb0 = r0 - q0w + 497;   // 80 rows cover j = r - q + 512
            bf16x8 kpf[5][2];
            #pragma unroll
            for (int t = 0; t < 5; ++t)
                #pragma unroll
                for (int kk = 0; kk < 2; ++kk)
                    kpf[t][kk] = *(const bf16x8*)(KPb + ((size_t)nh * POSLEN_ + jb0 + t * 16 + l15) * 64 + kk * 32 + hi * 8);
            #pragma unroll
            for (int t = 0; t < 5; ++t) {
                f32x4 d0 = {0.f, 0.f, 0.f, 0.f};
                #pragma unroll
                for (int kk = 0; kk < 2; ++kk)
                    d0 = __builtin_amdgcn_mfma_f32_16x16x32_bf16(apb[kk], kpf[t][kk], d0, 0, 0, 0);
                *(f32x4*)(&Dlf[(t * 16 + l15) * 20 + hi * 4]) = d0;
            }
        }
        float pav[4][4];
        if (ISQ) {
            #pragma unroll
            for (int fc = 0; fc < 4; ++fc)
                #pragma unroll
                for (int r = 0; r < 4; ++r) {
                    int qq = hi * 4 + r;
                    int j = (r0 + fc * 16 + l15) - qg[r] + 512;
                    pav[fc][r] = bf2f(PA[((size_t)nh * P_ + q0w + qq) * 1536 + j]);
                }
        }

        // ---- phase 3: V fragments issued BEFORE softmax (latency hides under exp chain) ----
        bf16x8 vf[2][4];
        #pragma unroll
        for (int kk = 0; kk < 2; ++kk)
            #pragma unroll
            for (int dj = 0; dj < 4; ++dj)
                vf[kk][dj] = *(const bf16x8*)(Vtb + ((size_t)nh * 64 + dj * 16 + l15) * 1024 + r0 + kk * 32 + hi * 8);

        // ---- fixed-max softmax: p = 2^(s_tot*EXSC + EXBI) ----
        #pragma unroll
        for (int fc = 0; fc < 4; ++fc) {
            #pragma unroll
            for (int r = 0; r < 4; ++r) {
                int qq = hi * 4 + r;
                int rr = fc * 16 + l15;
                float dval = ISQ ? pav[fc][r] : Dlf[(rr - qq + 15) * 20 + qq];
                int sel = (int)((sw[r] >> rr) & 1);
                float st = s[fc][r] + dval + (sel ? sd[1][r] : sd[0][r]);
                float v = fmaf(st, EXSC, EXBI);
                bool masked = (r0 + rr) >= qg[r] + (ISQ ? 512 : 513);
                v = masked ? -INFINITY : v;
                float pv = exp2f(v);
                ushort us = f2bf(pv);
                psum[r] += bf2f(us);
                int row = hi * 4 + r;
                int cc = rr ^ ((row & 7) << 3);
                Pl[row * 64 + cc] = us;
            }
        }

        // ---- PV ----
        #pragma unroll
        for (int kk = 0; kk < 2; ++kk) {
            int cc = (kk * 32 + hi * 8) ^ ((l15 & 7) << 3);
            bf16x8 pa = *(const bf16x8*)&Pl[l15 * 64 + cc];
            #pragma unroll
            for (int dj = 0; dj < 4; ++dj)
                acc[dj] = __builtin_amdgcn_mfma_f32_16x16x32_bf16(pa, vf[kk][dj], acc[dj], 0, 0, 0);
        }
    }

    // final psum reduce over the 16 column-lanes
    #pragma unroll
    for (int r = 0; r < 4; ++r) {
        #pragma unroll
        for (int d = 1; d < 16; d <<= 1) psum[r] += __shfl_xor(psum[r], d, 64);
    }

    // write partials (2 parts per row)
    #pragma unroll
    for (int r = 0; r < 4; ++r) {
        int qrow = q0w + hi * 4 + r;
        size_t rowg = ISQ ? (32768 + (size_t)nh * P_ + qrow) : ((size_t)nh * Q_ + qrow);
        float* base = Pp + (rowg * 2 + part) * 72;
        #pragma unroll
        for (int dj = 0; dj < 4; ++dj)
            base[dj * 16 + l15] = acc[dj][r];
        if (l15 == 0) base[64] = psum[r];
    }
}

// combine r-split partials (2 parts)
__global__ __launch_bounds__(256) void combine_k(const float* __restrict__ Pp,
                                                 ushort* __restrict__ AOc,
                                                 ushort* __restrict__ AOq) {
    int idx = blockIdx.x * 256 + threadIdx.x;
    int row = idx >> 6, d = idx & 63;
    const float* b0 = Pp + ((size_t)row * 2 + 0) * 72;
    const float* b1 = b0 + 72;
    float l = b0[64] + b1[64];
    ushort o = f2bf((b0[d] + b1[d]) / l);
    if (row < 32768) {
        int n = row >> 13, h = (row >> 9) & 15, q = row & 511;
        AOc[((size_t)(n * Q_ + q)) * 1024 + h * 64 + d] = o;
    } else {
        int r2 = row - 32768;
        int n = r2 >> 11, h = (r2 >> 7) & 15, p = r2 & 127;
        AOq[((size_t)(n * P_ + p)) * 1024 + h * 64 + d] = o;
    }
}

extern "C" void kernel_launch(void* const* d_in, const int* in_sizes, int n_in,
                              void* d_out, int out_size, void* d_ws, size_t ws_size,
                              hipStream_t stream) {
    const float* content = (const float*)d_in[0];
    const float* query   = (const float*)d_in[1];
    const float* posenc  = (const float*)d_in[2];
    const float* segenc  = (const float*)d_in[3];
    const int*   segmat  = (const int*)d_in[4];
    const float* tmap    = (const float*)d_in[5];
    const float* cbias   = (const float*)d_in[8];
    const float* pbias   = (const float*)d_in[9];
    const float* sbias   = (const float*)d_in[10];
    const float* mems    = (const float*)d_in[11];
    const float* Wq      = (const float*)d_in[12];
    const float* Wkc     = (const float*)d_in[13];
    const float* Wv      = (const float*)d_in[14];
    const float* Wkp     = (const float*)d_in[15];
    const float* Wo      = (const float*)d_in[16];
    float* out = (float*)d_out;

    char* p = (char*)d_ws;
    auto alloc = [&](size_t bytes) { char* r = p; p += (bytes + 255) & ~(size_t)255; return r; };
    ushort* ctx_bf  = (ushort*)alloc((size_t)B_ * R_ * 1024 * 2);
    ushort* pos_bf  = (ushort*)alloc((size_t)B_ * POSLEN_ * 1024 * 2);
    ushort* qry_bf  = (ushort*)alloc((size_t)B_ * P_ * 1024 * 2);
    ushort* Wq_t    = (ushort*)alloc(1024 * 1024 * 2);
    ushort* Wkc_t   = (ushort*)alloc(1024 * 1024 * 2);
    ushort* Wv_t    = (ushort*)alloc(1024 * 1024 * 2);
    ushort* Wkp_t   = (ushort*)alloc(1024 * 1024 * 2);
    ushort* Wo_t    = (ushort*)alloc(1024 * 1024 * 2);
    ushort* KC_bf   = (ushort*)alloc((size_t)B_ * 16 * R_ * 64 * 2);
    ushort* Vt_bf   = (ushort*)alloc((size_t)B_ * 16 * 64 * R_ * 2);
    ushort* KP_bf   = (ushort*)alloc((size_t)B_ * 16 * POSLEN_ * 64 * 2);
    ushort* Qc_cb   = (ushort*)alloc((size_t)B_ * 16 * Q_ * 64 * 2);
    ushort* Qc_pb   = (ushort*)alloc((size_t)B_ * 16 * Q_ * 64 * 2);
    ushort* Qq_cb   = (ushort*)alloc((size_t)B_ * 16 * P_ * 64 * 2);
    ushort* Qq_pb   = (ushort*)alloc((size_t)B_ * 16 * P_ * 64 * 2);
    ushort* PAq_bf  = (ushort*)alloc((size_t)B_ * 16 * P_ * 1536 * 2);
    ushort* AOc_bf  = (ushort*)alloc((size_t)B_ * Q_ * 1024 * 2);
    ushort* AOq_bf  = (ushort*)alloc((size_t)B_ * P_ * 1024 * 2);
    ushort* seg_bf  = (ushort*)alloc(16 * 16 * 64 * 2);
    float*  segc    = (float*)alloc(32 * 4);
    u64*    pseg    = (u64*)alloc((size_t)B_ * Q_ * 16 * 8);
    int*    tpos    = (int*)alloc(B_ * P_ * 4);
    // DEDICATED r-split partials buffer: 40960 rows x 2 parts x 72 f32 = 23.6 MB.
    float* Pp = (float*)alloc((size_t)40960 * 2 * 72 * 4);

    // merged prep (one dispatch; content is read via ctx_bf, no separate copy)
    prep_all<<<18691, 256, 0, stream>>>(content, mems, posenc, query,
                                        ctx_bf, pos_bf, qry_bf,
                                        Wq, Wkc, Wv, Wkp, Wo,
                                        Wq_t, Wkc_t, Wv_t, Wkp_t, Wo_t,
                                        segmat, pseg,
                                        segenc, cbias, sbias, seg_bf, segc,
                                        tmap, tpos);

    // all projections, one dispatch (128x64 tiles — R6 config)
    proj_all<<<dim3(16, 132), 256, 0, stream>>>(ctx_bf, pos_bf, qry_bf,
                                                Wkc_t, Wv_t, Wkp_t, Wq_t,
                                                KC_bf, Vt_bf, KP_bf,
                                                Qc_cb, Qc_pb, Qq_cb, Qq_pb,
                                                cbias, pbias);

    // query-stream shifted pos logits
    pa_gemm<<<dim3(12, 64), 256, 0, stream>>>(Qq_pb, KP_bf, PAq_bf);

    // barrier-free fused attention (measured optimum), L2-sized swizzle
    attn_uni<<<dim3(40, 32, 4), 64, 0, stream>>>(Qc_cb, Qc_pb, Qq_cb, KC_bf, KP_bf, Vt_bf,
                                                 seg_bf, segc, pseg, tpos, PAq_bf, Pp);

    // combine partials -> bf16 AO
    combine_k<<<10240, 256, 0, stream>>>(Pp, AOc_bf, AOq_bf);

    // output projection, one dispatch (128x64 tiles — R6 config)
    oproj<<<dim3(16, 20), 256, 0, stream>>>(AOc_bf, AOq_bf, Wo_t, out);

    (void)in_sizes; (void)n_in; (void)out_size; (void)ws_size;
}